// Round 3
// baseline (87.096 us; speedup 1.0000x reference)
//
#include <hip/hip_runtime.h>
#include <math.h>

// OscillatorBank: B=16, T=500, H=100, HOP=64 -> out [B, T*HOP] f32.
// phase(b, t*64+j, h) = 2pi*( frac(64*S_{t-1}[b,h]) + (j+1)*w_rev[b,t,h] ),
//   w_rev = h^(1+stretch)*f0 / SR  (cycles per sample),  S = prefix sum of w_rev.
// R2: synth inner loop is pure VALU (v_readlane broadcast + v_sin in revolutions);
//     no LDS anywhere. Scan in double (exact), packed float2 (w_rev, base_rev) rows.

#define OB_B 16
#define OB_T 500
#define OB_H 100
#define OB_HOP 64

constexpr double SR_D = 44100.0;

__device__ __forceinline__ float readlane_f(float v, int l) {
    return __builtin_bit_cast(float, __builtin_amdgcn_readlane(__builtin_bit_cast(int, v), l));
}

// Kernel 1: one wave per (b,h). Lane l handles t in [8l, 8l+8).
// w_rev = h^(1+stretch)*f0/SR in double (exp2 with wave-uniform log2(h)),
// wave shfl-scan of chunk sums, writes float2(w_rev, frac(64*S_{t-1})) at [bt*H + h].
__global__ void __launch_bounds__(256)
ob_scan_fused(const float* __restrict__ f0,
              const float* __restrict__ stretch,
              float2* __restrict__ wb)
{
    int wave = threadIdx.x >> 6;
    int lane = threadIdx.x & 63;
    int bh   = blockIdx.x * 4 + wave;      // 0..1599
    int b = bh / OB_H, h = bh % OB_H;
    double L = log2((double)(h + 1));      // wave-uniform
    const float* f0b = f0      + b * OB_T;
    const float* stb = stretch + b * OB_T;

    double w[8];
    double csum = 0.0;
    int t0 = lane * 8;
    #pragma unroll
    for (int k = 0; k < 8; ++k) {
        int t = t0 + k;
        double wv = 0.0;
        if (t < OB_T)
            wv = exp2((1.0 + (double)stb[t]) * L) * (double)f0b[t] * (1.0 / SR_D);
        w[k] = wv;
        csum += wv;
    }
    // inclusive wave scan of chunk sums (double shuffles)
    double incl = csum;
    #pragma unroll
    for (int off = 1; off < 64; off <<= 1) {
        double up = __shfl_up(incl, (unsigned)off, 64);
        if (lane >= off) incl += up;
    }
    double S = incl - csum;                // exclusive prefix: sum of w for t < t0
    #pragma unroll
    for (int k = 0; k < 8; ++k) {
        int t = t0 + k;
        if (t < OB_T) {
            double ph = 64.0 * S;
            ph -= trunc(ph);               // frac, in revolutions
            wb[(size_t)(b * OB_T + t) * OB_H + h] = make_float2((float)w[k], (float)ph);
            S += w[k];
        }
    }
}

// Kernel 2: 256 threads = 4 waves = 4 hops; lane j = sample in hop.
// Lane-resident (w,b,c) for h=lane and h=64+lane; broadcast via v_readlane.
__global__ void __launch_bounds__(256)
ob_synth(const float2* __restrict__ wb,
         const float* __restrict__ amps,
         const float* __restrict__ loud,
         float* __restrict__ out)
{
    int wave = threadIdx.x >> 6;
    int lane = threadIdx.x & 63;
    int bt   = blockIdx.x * 4 + wave;      // b*T + t
    const float2* row  = wb   + (size_t)bt * OB_H;
    const float*  arow = amps + (size_t)bt * OB_H;
    float ld = loud[bt] * (1.0f / OB_H);

    float2 wb0 = row[lane];
    float  c0  = (wb0.x > 0.5f) ? 0.0f : ld * arow[lane];
    float2 wb1 = make_float2(0.0f, 0.0f);
    float  c1  = 0.0f;
    if (lane < OB_H - 64) {                // 36 tail harmonics
        wb1 = row[64 + lane];
        c1  = (wb1.x > 0.5f) ? 0.0f : ld * arow[64 + lane];
    }

    float jf  = (float)(lane + 1);
    float acc = 0.0f;
    #pragma unroll
    for (int h = 0; h < 64; ++h) {
        float w = readlane_f(wb0.x, h);
        float b = readlane_f(wb0.y, h);
        float c = readlane_f(c0,   h);
        acc += c * __builtin_amdgcn_sinf(b + jf * w);   // v_sin_f32, revolutions
    }
    #pragma unroll
    for (int h = 0; h < OB_H - 64; ++h) {
        float w = readlane_f(wb1.x, h);
        float b = readlane_f(wb1.y, h);
        float c = readlane_f(c1,   h);
        acc += c * __builtin_amdgcn_sinf(b + jf * w);
    }
    out[(size_t)bt * OB_HOP + lane] = acc;  // out[b, t*64 + j]
}

extern "C" void kernel_launch(void* const* d_in, const int* in_sizes, int n_in,
                              void* d_out, int out_size, void* d_ws, size_t ws_size,
                              hipStream_t stream)
{
    const float* f0      = (const float*)d_in[0];
    const float* loud    = (const float*)d_in[1];
    const float* amps    = (const float*)d_in[2];
    const float* stretch = (const float*)d_in[3];

    float2* wbuf = (float2*)d_ws;          // 800000 * 8B = 6.4 MB
    float*  out  = (float*)d_out;

    ob_scan_fused<<<(OB_B * OB_H) / 4, 256, 0, stream>>>(f0, stretch, wbuf);
    ob_synth<<<(OB_B * OB_T) / 4, 256, 0, stream>>>(wbuf, amps, loud, out);
}